// Round 2
// baseline (1327.276 us; speedup 1.0000x reference)
//
#include <hip/hip_runtime.h>
#include <cstdint>
#include <cstddef>

#define DIN 128
#define HID 256
#define MODD 500
#define OUTD 100

typedef unsigned int uint;
typedef unsigned short ushort;
typedef __attribute__((ext_vector_type(8))) __bf16 bf16x8;
typedef __attribute__((ext_vector_type(4))) float f32x4;

__device__ __forceinline__ float bf2f(ushort u) {
    return __uint_as_float(((uint)u) << 16);
}
__device__ __forceinline__ ushort f2bf(float f) {
    uint u = __float_as_uint(f);
    return (ushort)((u + 0x7FFF + ((u >> 16) & 1)) >> 16);
}
__device__ __forceinline__ void async_copy16(const void* g, void* l) {
    __builtin_amdgcn_global_load_lds((const __attribute__((address_space(1))) void*)g,
                                     (__attribute__((address_space(3))) void*)l, 16, 0, 0);
}
__device__ __forceinline__ float tanh_fast(float x) {
    // x >= 0 in our use (softplus output); stable both ends anyway
    return 1.0f - 2.0f / (__expf(2.0f * x) + 1.0f);
}

// ---------------- degree / CSR build ----------------

__global__ void count_deg(const int* __restrict__ dst, int* __restrict__ deg, int E) {
    int e = blockIdx.x * blockDim.x + threadIdx.x;
    if (e < E) atomicAdd(&deg[dst[e]], 1);
}

__global__ void compute_dinv(const int* __restrict__ deg, float* __restrict__ dinv, int N) {
    int i = blockIdx.x * blockDim.x + threadIdx.x;
    if (i < N) dinv[i] = rsqrtf((float)deg[i] + 2.0f);
}

// 3-phase scan: per-block scan -> scan of block sums -> add offsets
__global__ void scan_block(const int* __restrict__ deg, int* __restrict__ rp,
                           int* __restrict__ bsum, int n) {
    __shared__ int wsum[16];
    int tid = threadIdx.x;
    int lane = tid & 63;
    int w = tid >> 6;
    int i = blockIdx.x * 1024 + tid;
    int v = (i < n) ? deg[i] : 0;
    int x = v;
    #pragma unroll
    for (int off = 1; off < 64; off <<= 1) {
        int t = __shfl_up(x, off);
        if (lane >= off) x += t;
    }
    if (lane == 63) wsum[w] = x;
    __syncthreads();
    if (tid == 0) {
        int s = 0;
        #pragma unroll
        for (int k = 0; k < 16; ++k) { int t = wsum[k]; wsum[k] = s; s += t; }
        bsum[blockIdx.x] = s;
    }
    __syncthreads();
    if (i < n) rp[i] = wsum[w] + (x - v);
}

__global__ void scan_bsums(int* __restrict__ bsum, int nb) {
    if (threadIdx.x == 0 && blockIdx.x == 0) {
        int s = 0;
        for (int k = 0; k < nb; ++k) { int t = bsum[k]; bsum[k] = s; s += t; }
        bsum[nb] = s;
    }
}

__global__ void scan_add(int* __restrict__ rp, const int* __restrict__ bsum, int n, int nb) {
    int i = blockIdx.x * blockDim.x + threadIdx.x;
    if (i < n) rp[i] += bsum[i >> 10];
    else if (i == n) rp[n] = bsum[nb];
}

// ---------------- binned edge scatter ----------------
// Buckets of 512 consecutive dst nodes occupy contiguous CSR ranges
// [rp[b*512], rp[(b+1)*512]). Pass 1 partitions edges into those ranges with
// per-block LDS histogramming (coalesced run writes, ~1 global atomic per
// (block,bucket)). Pass 2 builds final (src, weight) records per bucket with
// LDS cursors; random writes stay inside an L2-resident window, and the edge
// weight dinv[src]*dinv[dst] is fused here (dinv is 400KB -> L2 resident) so
// the aggregate kernels have no random dinv gather.
// Packing: src (<2^20) in low 20 bits, dst offset (<512) in bits 20..28.

#define BSH 9
#define MAXB 256
#define PCH 8192

__global__ void init_bucket_cursor(const int* __restrict__ rp, int* __restrict__ bcur,
                                   int NB) {
    int b = blockIdx.x * blockDim.x + threadIdx.x;
    if (b < NB) bcur[b] = rp[b << BSH];
}

__global__ __launch_bounds__(256)
void partition_edges(const int* __restrict__ src, const int* __restrict__ dst,
                     int* __restrict__ bcur, uint* __restrict__ pairBuf,
                     int E, int NB) {
    __shared__ int hist[MAXB];
    __shared__ int gbase[MAXB];
    int tid = threadIdx.x;
    int e0 = blockIdx.x * PCH;
    int e1 = min(e0 + PCH, E);
    for (int b = tid; b < NB; b += 256) hist[b] = 0;
    __syncthreads();
    for (int e = e0 + tid; e < e1; e += 256) {
        int d = dst[e];
        atomicAdd(&hist[d >> BSH], 1);
    }
    __syncthreads();
    for (int b = tid; b < NB; b += 256) {
        int h = hist[b];
        gbase[b] = h ? atomicAdd(&bcur[b], h) : 0;
        hist[b] = 0;
    }
    __syncthreads();
    for (int e = e0 + tid; e < e1; e += 256) {
        int d = dst[e];
        int s = src[e];
        int b = d >> BSH;
        int idx = gbase[b] + atomicAdd(&hist[b], 1);
        pairBuf[idx] = (uint)s | ((uint)(d & ((1 << BSH) - 1)) << 20);
    }
}

__global__ __launch_bounds__(512)
void bucket_scatter(const uint* __restrict__ pairBuf, const int* __restrict__ rp,
                    uint2* __restrict__ cw, const float* __restrict__ dinv, int N) {
    __shared__ int lcur[1 << BSH];
    int b = blockIdx.x;
    int n0 = b << BSH;
    int nn = min(1 << BSH, N - n0);
    int tid = threadIdx.x;
    for (int i = tid; i < nn; i += 512) lcur[i] = rp[n0 + i];
    __syncthreads();
    int start = rp[n0];
    int end = rp[min(n0 + (1 << BSH), N)];
    for (int e = start + tid; e < end; e += 512) {
        uint v = pairBuf[e];
        int doff = v >> 20;
        int s = v & 0xFFFFF;
        int pos = atomicAdd(&lcur[doff], 1);
        float w = dinv[s] * dinv[n0 + doff];
        uint2 rec;
        rec.x = (uint)s;
        rec.y = __float_as_uint(w);
        cw[pos] = rec;
    }
}

// ---------------- casts / transposes ----------------

__global__ void cast_f32_bf16(const float* __restrict__ src, ushort* __restrict__ dst, int n4) {
    int i = blockIdx.x * blockDim.x + threadIdx.x;
    if (i < n4) {
        float4 v = ((const float4*)src)[i];
        ushort4 o;
        o.x = f2bf(v.x); o.y = f2bf(v.y); o.z = f2bf(v.z); o.w = f2bf(v.w);
        ((ushort4*)dst)[i] = o;
    }
}

// src[K][N] fp32 -> dst[Npad][Kpad] bf16 (zero padded)
__global__ void transpose_cast(const float* __restrict__ src, ushort* __restrict__ dst,
                               int K, int N, int Kpad, int Npad) {
    int idx = blockIdx.x * blockDim.x + threadIdx.x;
    if (idx >= Npad * Kpad) return;
    int n = idx / Kpad, k = idx - n * Kpad;
    float v = (n < N && k < K) ? src[(size_t)k * N + n] : 0.0f;
    dst[idx] = f2bf(v);
}

// ---------------- aggregation (gather over CSR, bf16 rows, fp32 accum) ----------------
// Y[n] = 2*dinv[n]^2 * X[n] + sum_{e in in(n)} w[e] * X[src[e]]
// One wave per node; 8-deep unroll with a masked full-width tail group keeps
// 8 row-gathers in flight per wave (latency hiding). Edge weights come packed
// with the column index (uint2), so the inner loop has one indirect load only.

// D = 128 bf16: uint (2 bf16) per lane
__global__ void aggregate128(const ushort* __restrict__ X, ushort* __restrict__ Y,
                             const int* __restrict__ rp, const uint2* __restrict__ cw,
                             const float* __restrict__ dinv, int N) {
    int gw = blockIdx.x * (blockDim.x >> 6) + (threadIdx.x >> 6);
    int lane = threadIdx.x & 63;
    if (gw >= N) return;
    float di = dinv[gw];
    float sc = 2.0f * di * di;
    const uint* Xr = (const uint*)X;
    uint s = Xr[(size_t)gw * 64 + lane];
    float ax = sc * bf2f((ushort)(s & 0xFFFF));
    float ay = sc * bf2f((ushort)(s >> 16));
    int e = rp[gw], end = rp[gw + 1];
    for (int base = e; base < end; base += 8) {
        uint2 c[8];
        #pragma unroll
        for (int q = 0; q < 8; ++q) {
            int idx = base + q;
            c[q] = cw[idx < end ? idx : end - 1];
            if (idx >= end) c[q].y = 0;
        }
        uint v[8];
        #pragma unroll
        for (int q = 0; q < 8; ++q) v[q] = Xr[(size_t)c[q].x * 64 + lane];
        #pragma unroll
        for (int q = 0; q < 8; ++q) {
            float w = __uint_as_float(c[q].y);
            ax += w * bf2f((ushort)(v[q] & 0xFFFF));
            ay += w * bf2f((ushort)(v[q] >> 16));
        }
    }
    uint out = (uint)f2bf(ax) | ((uint)f2bf(ay) << 16);
    ((uint*)Y)[(size_t)gw * 64 + lane] = out;
}

// D = 256 bf16: uint2 (4 bf16) per lane
__global__ void aggregate256(const ushort* __restrict__ X, ushort* __restrict__ Y,
                             const int* __restrict__ rp, const uint2* __restrict__ cw,
                             const float* __restrict__ dinv, int N) {
    int gw = blockIdx.x * (blockDim.x >> 6) + (threadIdx.x >> 6);
    int lane = threadIdx.x & 63;
    if (gw >= N) return;
    float di = dinv[gw];
    float sc = 2.0f * di * di;
    const uint2* Xr = (const uint2*)X;
    uint2 s = Xr[(size_t)gw * 64 + lane];
    float a0 = sc * bf2f((ushort)(s.x & 0xFFFF));
    float a1 = sc * bf2f((ushort)(s.x >> 16));
    float a2 = sc * bf2f((ushort)(s.y & 0xFFFF));
    float a3 = sc * bf2f((ushort)(s.y >> 16));
    int e = rp[gw], end = rp[gw + 1];
    for (int base = e; base < end; base += 8) {
        uint2 c[8];
        #pragma unroll
        for (int q = 0; q < 8; ++q) {
            int idx = base + q;
            c[q] = cw[idx < end ? idx : end - 1];
            if (idx >= end) c[q].y = 0;
        }
        uint2 v[8];
        #pragma unroll
        for (int q = 0; q < 8; ++q) v[q] = Xr[(size_t)c[q].x * 64 + lane];
        #pragma unroll
        for (int q = 0; q < 8; ++q) {
            float w = __uint_as_float(c[q].y);
            a0 += w * bf2f((ushort)(v[q].x & 0xFFFF));
            a1 += w * bf2f((ushort)(v[q].x >> 16));
            a2 += w * bf2f((ushort)(v[q].y & 0xFFFF));
            a3 += w * bf2f((ushort)(v[q].y >> 16));
        }
    }
    uint2 out;
    out.x = (uint)f2bf(a0) | ((uint)f2bf(a1) << 16);
    out.y = (uint)f2bf(a2) | ((uint)f2bf(a3) << 16);
    ((uint2*)Y)[(size_t)gw * 64 + lane] = out;
}

// ---------------- bf16 MFMA GEMM (m97 structure) ----------------
// C[M,Nact] = epi(A[M,K]_bf16 @ BT[Npad,K]_bf16^T + bias)
// BM=128, BN=128, BK=32, 256 threads = 4 waves, each wave 64x64 (4x4 MFMA tiles)
// MODE 0: relu -> bf16 store; MODE 1: softplus -> f32 store; MODE 2: plain -> f32 store

template<int K, int MODE>
__global__ __launch_bounds__(256)
void gemm_bt(const ushort* __restrict__ A, const ushort* __restrict__ BT,
             const float* __restrict__ bias, void* __restrict__ Cout,
             int M, int Nact, int ldc) {
    __shared__ ushort sA[128 * 32];
    __shared__ ushort sB[128 * 32];
    int tid = threadIdx.x;
    int lane = tid & 63;
    int w = tid >> 6;
    int wr = w >> 1, wc = w & 1;
    int row0 = blockIdx.y * 128;
    int col0 = blockIdx.x * 128;
    f32x4 acc[4][4] = {};

    for (int kt = 0; kt < K; kt += 32) {
        if (kt) __syncthreads();
        #pragma unroll
        for (int L = 0; L < 2; ++L) {
            int cb = L * 256 + w * 64;
            int c = cb + lane;
            int r = c >> 2;
            int ko = (c & 3) * 8;
            int rr = min(row0 + r, M - 1);
            async_copy16(A + (size_t)rr * K + kt + ko, sA + (size_t)cb * 8);
        }
        #pragma unroll
        for (int L = 0; L < 2; ++L) {
            int cb = L * 256 + w * 64;
            int c = cb + lane;
            int nr = c >> 2;
            int ko = (c & 3) * 8;
            async_copy16(BT + (size_t)(col0 + nr) * K + kt + ko, sB + (size_t)cb * 8);
        }
        __syncthreads();
        bf16x8 af[4], bfr[4];
        #pragma unroll
        for (int i = 0; i < 4; ++i) {
            int row = wr * 64 + i * 16 + (lane & 15);
            af[i] = *(const bf16x8*)(sA + row * 32 + (lane >> 4) * 8);
        }
        #pragma unroll
        for (int j = 0; j < 4; ++j) {
            int n = wc * 64 + j * 16 + (lane & 15);
            bfr[j] = *(const bf16x8*)(sB + n * 32 + (lane >> 4) * 8);
        }
        #pragma unroll
        for (int i = 0; i < 4; ++i)
            #pragma unroll
            for (int j = 0; j < 4; ++j)
                acc[i][j] = __builtin_amdgcn_mfma_f32_16x16x32_bf16(af[i], bfr[j], acc[i][j], 0, 0, 0);
    }

    #pragma unroll
    for (int i = 0; i < 4; ++i) {
        #pragma unroll
        for (int j = 0; j < 4; ++j) {
            int col = col0 + wc * 64 + j * 16 + (lane & 15);
            if (col >= Nact) continue;
            float bv = bias[col];
            #pragma unroll
            for (int r = 0; r < 4; ++r) {
                int row = row0 + wr * 64 + i * 16 + (lane >> 4) * 4 + r;
                if (row >= M) continue;
                float v = acc[i][j][r] + bv;
                if (MODE == 0) {
                    v = fmaxf(v, 0.0f);
                    ((ushort*)Cout)[(size_t)row * ldc + col] = f2bf(v);
                } else if (MODE == 1) {
                    v = (v > 20.0f) ? v : log1pf(expf(v));
                    ((float*)Cout)[(size_t)row * ldc + col] = v;
                } else {
                    ((float*)Cout)[(size_t)row * ldc + col] = v;
                }
            }
        }
    }
}

// GEMM3: A = tanh(sp * mr) computed on the fly from fp32 mr[M,500]; K padded to 512.
__global__ __launch_bounds__(256)
void gemm_tanh(const float* __restrict__ Ain, const ushort* __restrict__ BT,
               const float* __restrict__ bias, float* __restrict__ Cout,
               int M, int Nact, int ldc, const float* __restrict__ thr) {
    const int K = 512, KA = 500;
    __shared__ ushort sA[128 * 32];
    __shared__ ushort sB[128 * 32];
    int tid = threadIdx.x;
    int lane = tid & 63;
    int w = tid >> 6;
    int wr = w >> 1, wc = w & 1;
    int row0 = blockIdx.y * 128;
    int col0 = blockIdx.x * 128;
    float t = *thr;
    float sp = (t > 20.0f) ? t : log1pf(expf(t));
    f32x4 acc[4][4] = {};

    int r = tid >> 1;
    int kh = (tid & 1) * 16;
    int rr_a = min(row0 + r, M - 1);
    const float* arow = Ain + (size_t)rr_a * KA;

    for (int kt = 0; kt < K; kt += 32) {
        if (kt) __syncthreads();
        // A: manual stage with fused tanh + cast
        float vals[16];
        int kb = kt + kh;
        if (kb + 16 <= KA) {
            #pragma unroll
            for (int q = 0; q < 4; ++q) {
                float4 f = *(const float4*)(arow + kb + q * 4);
                vals[q * 4 + 0] = f.x; vals[q * 4 + 1] = f.y;
                vals[q * 4 + 2] = f.z; vals[q * 4 + 3] = f.w;
            }
        } else {
            #pragma unroll
            for (int q = 0; q < 16; ++q) {
                int k = kb + q;
                vals[q] = (k < KA) ? arow[k] : 0.0f;
            }
        }
        ushort us[16];
        #pragma unroll
        for (int q = 0; q < 16; ++q) us[q] = f2bf(tanh_fast(sp * vals[q]));
        *(uint4*)(sA + r * 32 + kh) = *(const uint4*)(us);
        *(uint4*)(sA + r * 32 + kh + 8) = *(const uint4*)(us + 8);
        // B: async stage
        #pragma unroll
        for (int L = 0; L < 2; ++L) {
            int cb = L * 256 + w * 64;
            int c = cb + lane;
            int nr = c >> 2;
            int ko = (c & 3) * 8;
            async_copy16(BT + (size_t)(col0 + nr) * K + kt + ko, sB + (size_t)cb * 8);
        }
        __syncthreads();
        bf16x8 af[4], bfr[4];
        #pragma unroll
        for (int i = 0; i < 4; ++i) {
            int row = wr * 64 + i * 16 + (lane & 15);
            af[i] = *(const bf16x8*)(sA + row * 32 + (lane >> 4) * 8);
        }
        #pragma unroll
        for (int j = 0; j < 4; ++j) {
            int n = wc * 64 + j * 16 + (lane & 15);
            bfr[j] = *(const bf16x8*)(sB + n * 32 + (lane >> 4) * 8);
        }
        #pragma unroll
        for (int i = 0; i < 4; ++i)
            #pragma unroll
            for (int j = 0; j < 4; ++j)
                acc[i][j] = __builtin_amdgcn_mfma_f32_16x16x32_bf16(af[i], bfr[j], acc[i][j], 0, 0, 0);
    }

    #pragma unroll
    for (int i = 0; i < 4; ++i) {
        #pragma unroll
        for (int j = 0; j < 4; ++j) {
            int col = col0 + wc * 64 + j * 16 + (lane & 15);
            if (col >= Nact) continue;
            float bv = bias[col];
            #pragma unroll
            for (int rix = 0; rix < 4; ++rix) {
                int row = row0 + wr * 64 + i * 16 + (lane >> 4) * 4 + rix;
                if (row >= M) continue;
                Cout[(size_t)row * ldc + col] = acc[i][j][rix] + bv;
            }
        }
    }
}

// ---------------- launch ----------------

extern "C" void kernel_launch(void* const* d_in, const int* in_sizes, int n_in,
                              void* d_out, int out_size, void* d_ws, size_t ws_size,
                              hipStream_t stream) {
    const float* x    = (const float*)d_in[0];
    const int*   ei   = (const int*)d_in[1];
    const float* W1   = (const float*)d_in[2];
    const float* b1   = (const float*)d_in[3];
    const float* W2   = (const float*)d_in[4];
    const float* b2   = (const float*)d_in[5];
    const float* Wout = (const float*)d_in[6];
    const float* bout = (const float*)d_in[7];
    const float* thr  = (const float*)d_in[8];

    int N = in_sizes[0] / DIN;
    int E = in_sizes[1] / 2;
    const int* srcI = ei;
    const int* dstI = ei + E;

    char* wsp = (char*)d_ws;
    size_t o = 0;
    auto alloc = [&](size_t bytes) -> void* {
        void* p = wsp + o;
        o = (o + bytes + 255) & ~(size_t)255;
        return p;
    };
    int*    deg   = (int*)alloc((size_t)N * 4);
    float*  dinv  = (float*)alloc((size_t)N * 4);
    int*    rp    = (int*)alloc((size_t)(N + 1) * 4);
    int*    bsum  = (int*)alloc(1024);
    int*    bcur  = (int*)alloc(MAXB * 4);
    uint2*  cw    = (uint2*)alloc((size_t)E * 8);          // packed (src, weight)
    ushort* W1T   = (ushort*)alloc((size_t)256 * 128 * 2);
    ushort* W2T   = (ushort*)alloc((size_t)512 * 256 * 2);
    ushort* WoutT = (ushort*)alloc((size_t)128 * 512 * 2);
    ushort* bufA  = (ushort*)alloc((size_t)N * 256 * 2);  // xbf+xa, later ha
    ushort* hbuf  = (ushort*)alloc((size_t)N * 256 * 2);  // h bf16 (pairBuf before gemm1)

    ushort* xbf = bufA;                       // [N,128] bf16
    ushort* xa  = bufA + (size_t)N * 128;     // [N,128] bf16
    ushort* ha  = bufA;                       // [N,256] bf16 (reuses xbf+xa)
    uint* pairBuf = (uint*)hbuf;              // [E] packed edges (dead before gemm1 writes hbuf)

    float* mr   = (float*)d_out;                    // [N,500]
    float* yout = (float*)d_out + (size_t)N * MODD; // [N,100]

    int mtiles = (N + 127) / 128;
    int NB = (N + (1 << BSH) - 1) >> BSH;           // node-range buckets (196 for N=100K)

    // --- CSR build ---
    hipMemsetAsync(deg, 0, (size_t)N * 4, stream);
    count_deg<<<(E + 255) / 256, 256, 0, stream>>>(dstI, deg, E);
    compute_dinv<<<(N + 255) / 256, 256, 0, stream>>>(deg, dinv, N);
    int nb = (N + 1023) / 1024;
    scan_block<<<nb, 1024, 0, stream>>>(deg, rp, bsum, N);
    scan_bsums<<<1, 64, 0, stream>>>(bsum, nb);
    scan_add<<<(N + 256) / 256, 256, 0, stream>>>(rp, bsum, N, nb);
    // binned 2-pass edge scatter (weights fused in pass 2)
    init_bucket_cursor<<<1, 256, 0, stream>>>(rp, bcur, NB);
    partition_edges<<<(E + PCH - 1) / PCH, 256, 0, stream>>>(srcI, dstI, bcur, pairBuf, E, NB);
    bucket_scatter<<<NB, 512, 0, stream>>>(pairBuf, rp, cw, dinv, N);

    // --- weight prep ---
    cast_f32_bf16<<<((N * DIN / 4) + 255) / 256, 256, 0, stream>>>(x, xbf, N * DIN / 4);
    transpose_cast<<<(256 * 128 + 255) / 256, 256, 0, stream>>>(W1, W1T, 128, 256, 128, 256);
    transpose_cast<<<(512 * 256 + 255) / 256, 256, 0, stream>>>(W2, W2T, 256, 500, 256, 512);
    transpose_cast<<<(128 * 512 + 255) / 256, 256, 0, stream>>>(Wout, WoutT, 500, 100, 512, 128);

    // --- conv1 ---
    aggregate128<<<(N + 3) / 4, 256, 0, stream>>>(xbf, xa, rp, cw, dinv, N);
    gemm_bt<128, 0><<<dim3(2, mtiles), 256, 0, stream>>>(xa, W1T, b1, hbuf, N, HID, HID);

    // --- conv2 ---
    aggregate256<<<(N + 3) / 4, 256, 0, stream>>>(hbuf, ha, rp, cw, dinv, N);
    gemm_bt<256, 1><<<dim3(4, mtiles), 256, 0, stream>>>(ha, W2T, b2, mr, N, MODD, MODD);

    // --- head: y = tanh(sp*mr) @ Wout + bout ---
    gemm_tanh<<<dim3(1, mtiles), 256, 0, stream>>>(mr, WoutT, bout, yout, N, OUTD, OUTD, thr);
}

// Round 3
// 1140.088 us; speedup vs baseline: 1.1642x; 1.1642x over previous
//
#include <hip/hip_runtime.h>
#include <cstdint>
#include <cstddef>

#define DIN 128
#define HID 256
#define MODD 500
#define OUTD 100

typedef unsigned int uint;
typedef unsigned short ushort;
typedef __attribute__((ext_vector_type(8))) __bf16 bf16x8;
typedef __attribute__((ext_vector_type(4))) float f32x4;

__device__ __forceinline__ float bf2f(ushort u) {
    return __uint_as_float(((uint)u) << 16);
}
__device__ __forceinline__ ushort f2bf(float f) {
    uint u = __float_as_uint(f);
    return (ushort)((u + 0x7FFF + ((u >> 16) & 1)) >> 16);
}
__device__ __forceinline__ void async_copy16(const void* g, void* l) {
    __builtin_amdgcn_global_load_lds((const __attribute__((address_space(1))) void*)g,
                                     (__attribute__((address_space(3))) void*)l, 16, 0, 0);
}
__device__ __forceinline__ float tanh_fast(float x) {
    // x >= 0 in our use (softplus output); stable both ends anyway
    return 1.0f - 2.0f / (__expf(2.0f * x) + 1.0f);
}
// stable fast softplus: max(v,0) + log(1 + exp(-|v|)); ~6 VALU ops vs libm's ~60+
__device__ __forceinline__ float softplus_fast(float v) {
    return fmaxf(v, 0.0f) + __logf(1.0f + __expf(-fabsf(v)));
}

// ---------------- degree / CSR build ----------------

__global__ void count_deg(const int* __restrict__ dst, int* __restrict__ deg, int E) {
    int e = blockIdx.x * blockDim.x + threadIdx.x;
    if (e < E) atomicAdd(&deg[dst[e]], 1);
}

__global__ void compute_dinv(const int* __restrict__ deg, float* __restrict__ dinv, int N) {
    int i = blockIdx.x * blockDim.x + threadIdx.x;
    if (i < N) dinv[i] = rsqrtf((float)deg[i] + 2.0f);
}

// 3-phase scan: per-block scan -> scan of block sums -> add offsets
__global__ void scan_block(const int* __restrict__ deg, int* __restrict__ rp,
                           int* __restrict__ bsum, int n) {
    __shared__ int wsum[16];
    int tid = threadIdx.x;
    int lane = tid & 63;
    int w = tid >> 6;
    int i = blockIdx.x * 1024 + tid;
    int v = (i < n) ? deg[i] : 0;
    int x = v;
    #pragma unroll
    for (int off = 1; off < 64; off <<= 1) {
        int t = __shfl_up(x, off);
        if (lane >= off) x += t;
    }
    if (lane == 63) wsum[w] = x;
    __syncthreads();
    if (tid == 0) {
        int s = 0;
        #pragma unroll
        for (int k = 0; k < 16; ++k) { int t = wsum[k]; wsum[k] = s; s += t; }
        bsum[blockIdx.x] = s;
    }
    __syncthreads();
    if (i < n) rp[i] = wsum[w] + (x - v);
}

__global__ void scan_bsums(int* __restrict__ bsum, int nb) {
    if (threadIdx.x == 0 && blockIdx.x == 0) {
        int s = 0;
        for (int k = 0; k < nb; ++k) { int t = bsum[k]; bsum[k] = s; s += t; }
        bsum[nb] = s;
    }
}

__global__ void scan_add(int* __restrict__ rp, const int* __restrict__ bsum, int n, int nb) {
    int i = blockIdx.x * blockDim.x + threadIdx.x;
    if (i < n) rp[i] += bsum[i >> 10];
    else if (i == n) rp[n] = bsum[nb];
}

// ---------------- binned edge scatter ----------------
// Buckets of 512 consecutive dst nodes occupy contiguous CSR ranges
// [rp[b*512], rp[(b+1)*512]). Pass 1 partitions edges into those ranges with
// per-block LDS histogramming (coalesced run writes, ~1 global atomic per
// (block,bucket)). Pass 2 builds final col[] per bucket with LDS cursors, so
// random writes stay inside a ~64KB L2-resident window.
// Packing: src (<2^20) in low 20 bits, dst offset (<512) in bits 20..28.

#define BSH 9
#define MAXB 256
#define PCH 8192

__global__ void init_bucket_cursor(const int* __restrict__ rp, int* __restrict__ bcur,
                                   int NB) {
    int b = blockIdx.x * blockDim.x + threadIdx.x;
    if (b < NB) bcur[b] = rp[b << BSH];
}

__global__ __launch_bounds__(256)
void partition_edges(const int* __restrict__ src, const int* __restrict__ dst,
                     int* __restrict__ bcur, uint* __restrict__ pairBuf,
                     int E, int NB) {
    __shared__ int hist[MAXB];
    __shared__ int gbase[MAXB];
    int tid = threadIdx.x;
    int e0 = blockIdx.x * PCH;
    int e1 = min(e0 + PCH, E);
    for (int b = tid; b < NB; b += 256) hist[b] = 0;
    __syncthreads();
    for (int e = e0 + tid; e < e1; e += 256) {
        int d = dst[e];
        atomicAdd(&hist[d >> BSH], 1);
    }
    __syncthreads();
    for (int b = tid; b < NB; b += 256) {
        int h = hist[b];
        gbase[b] = h ? atomicAdd(&bcur[b], h) : 0;
        hist[b] = 0;
    }
    __syncthreads();
    for (int e = e0 + tid; e < e1; e += 256) {
        int d = dst[e];
        int s = src[e];
        int b = d >> BSH;
        int idx = gbase[b] + atomicAdd(&hist[b], 1);
        pairBuf[idx] = (uint)s | ((uint)(d & ((1 << BSH) - 1)) << 20);
    }
}

__global__ __launch_bounds__(512)
void bucket_scatter(const uint* __restrict__ pairBuf, const int* __restrict__ rp,
                    int* __restrict__ col, int N) {
    __shared__ int lcur[1 << BSH];
    int b = blockIdx.x;
    int n0 = b << BSH;
    int nn = min(1 << BSH, N - n0);
    int tid = threadIdx.x;
    for (int i = tid; i < nn; i += 512) lcur[i] = rp[n0 + i];
    __syncthreads();
    int start = rp[n0];
    int end = rp[min(n0 + (1 << BSH), N)];
    for (int e = start + tid; e < end; e += 512) {
        uint v = pairBuf[e];
        int doff = v >> 20;
        int s = v & 0xFFFFF;
        int pos = atomicAdd(&lcur[doff], 1);
        col[pos] = s;
    }
}

// ---------------- casts / transposes ----------------

__global__ void cast_f32_bf16(const float* __restrict__ src, ushort* __restrict__ dst, int n4) {
    int i = blockIdx.x * blockDim.x + threadIdx.x;
    if (i < n4) {
        float4 v = ((const float4*)src)[i];
        ushort4 o;
        o.x = f2bf(v.x); o.y = f2bf(v.y); o.z = f2bf(v.z); o.w = f2bf(v.w);
        ((ushort4*)dst)[i] = o;
    }
}

// src[K][N] fp32 -> dst[Npad][Kpad] bf16 (zero padded)
__global__ void transpose_cast(const float* __restrict__ src, ushort* __restrict__ dst,
                               int K, int N, int Kpad, int Npad) {
    int idx = blockIdx.x * blockDim.x + threadIdx.x;
    if (idx >= Npad * Kpad) return;
    int n = idx / Kpad, k = idx - n * Kpad;
    float v = (n < N && k < K) ? src[(size_t)k * N + n] : 0.0f;
    dst[idx] = f2bf(v);
}

// ---------------- aggregation (gather over CSR, bf16 rows, fp32 accum) ----------------
// Y[n] = 2*dinv[n]^2 * X[n] + sum_{e in in(n)} dinv[src]*dinv[n] * X[src]
// (R1-proven form: 2-deep unroll; gather is BW-ceiling-bound, deeper MLP hurt in R2)

// D = 128 bf16: one wave/node, uint (2 bf16) per lane
__global__ void aggregate128(const ushort* __restrict__ X, ushort* __restrict__ Y,
                             const int* __restrict__ rp, const int* __restrict__ col,
                             const float* __restrict__ dinv, int N) {
    int gw = blockIdx.x * (blockDim.x >> 6) + (threadIdx.x >> 6);
    int lane = threadIdx.x & 63;
    if (gw >= N) return;
    float di = dinv[gw];
    float sc = 2.0f * di * di;
    const uint* Xr = (const uint*)X;
    uint s = Xr[(size_t)gw * 64 + lane];
    float ax = sc * bf2f((ushort)(s & 0xFFFF));
    float ay = sc * bf2f((ushort)(s >> 16));
    int e = rp[gw], end = rp[gw + 1];
    for (; e + 2 <= end; e += 2) {
        int c0 = col[e], c1 = col[e + 1];
        float w0 = dinv[c0] * di, w1 = dinv[c1] * di;
        uint v0 = Xr[(size_t)c0 * 64 + lane];
        uint v1 = Xr[(size_t)c1 * 64 + lane];
        ax += w0 * bf2f((ushort)(v0 & 0xFFFF));
        ay += w0 * bf2f((ushort)(v0 >> 16));
        ax += w1 * bf2f((ushort)(v1 & 0xFFFF));
        ay += w1 * bf2f((ushort)(v1 >> 16));
    }
    if (e < end) {
        int c0 = col[e];
        float w0 = dinv[c0] * di;
        uint v0 = Xr[(size_t)c0 * 64 + lane];
        ax += w0 * bf2f((ushort)(v0 & 0xFFFF));
        ay += w0 * bf2f((ushort)(v0 >> 16));
    }
    uint out = (uint)f2bf(ax) | ((uint)f2bf(ay) << 16);
    ((uint*)Y)[(size_t)gw * 64 + lane] = out;
}

// D = 256 bf16: one wave/node, uint2 (4 bf16) per lane
__global__ void aggregate256(const ushort* __restrict__ X, ushort* __restrict__ Y,
                             const int* __restrict__ rp, const int* __restrict__ col,
                             const float* __restrict__ dinv, int N) {
    int gw = blockIdx.x * (blockDim.x >> 6) + (threadIdx.x >> 6);
    int lane = threadIdx.x & 63;
    if (gw >= N) return;
    float di = dinv[gw];
    float sc = 2.0f * di * di;
    const uint2* Xr = (const uint2*)X;
    uint2 s = Xr[(size_t)gw * 64 + lane];
    float a0 = sc * bf2f((ushort)(s.x & 0xFFFF));
    float a1 = sc * bf2f((ushort)(s.x >> 16));
    float a2 = sc * bf2f((ushort)(s.y & 0xFFFF));
    float a3 = sc * bf2f((ushort)(s.y >> 16));
    int e = rp[gw], end = rp[gw + 1];
    for (; e + 2 <= end; e += 2) {
        int c0 = col[e], c1 = col[e + 1];
        float w0 = dinv[c0] * di, w1 = dinv[c1] * di;
        uint2 v0 = Xr[(size_t)c0 * 64 + lane];
        uint2 v1 = Xr[(size_t)c1 * 64 + lane];
        a0 += w0 * bf2f((ushort)(v0.x & 0xFFFF));
        a1 += w0 * bf2f((ushort)(v0.x >> 16));
        a2 += w0 * bf2f((ushort)(v0.y & 0xFFFF));
        a3 += w0 * bf2f((ushort)(v0.y >> 16));
        a0 += w1 * bf2f((ushort)(v1.x & 0xFFFF));
        a1 += w1 * bf2f((ushort)(v1.x >> 16));
        a2 += w1 * bf2f((ushort)(v1.y & 0xFFFF));
        a3 += w1 * bf2f((ushort)(v1.y >> 16));
    }
    if (e < end) {
        int c0 = col[e];
        float w0 = dinv[c0] * di;
        uint2 v0 = Xr[(size_t)c0 * 64 + lane];
        a0 += w0 * bf2f((ushort)(v0.x & 0xFFFF));
        a1 += w0 * bf2f((ushort)(v0.x >> 16));
        a2 += w0 * bf2f((ushort)(v0.y & 0xFFFF));
        a3 += w0 * bf2f((ushort)(v0.y >> 16));
    }
    uint2 out;
    out.x = (uint)f2bf(a0) | ((uint)f2bf(a1) << 16);
    out.y = (uint)f2bf(a2) | ((uint)f2bf(a3) << 16);
    ((uint2*)Y)[(size_t)gw * 64 + lane] = out;
}

// ---------------- bf16 MFMA GEMM (m97 structure) ----------------
// C[M,Nact] = epi(A[M,K]_bf16 @ BT[Npad,K]_bf16^T + bias)
// BM=128, BN=128, BK=32, 256 threads = 4 waves, each wave 64x64 (4x4 MFMA tiles)
// MODE 0: relu -> bf16 store; MODE 1: softplus -> f32 store; MODE 2: plain -> f32 store

template<int K, int MODE>
__global__ __launch_bounds__(256)
void gemm_bt(const ushort* __restrict__ A, const ushort* __restrict__ BT,
             const float* __restrict__ bias, void* __restrict__ Cout,
             int M, int Nact, int ldc) {
    __shared__ ushort sA[128 * 32];
    __shared__ ushort sB[128 * 32];
    int tid = threadIdx.x;
    int lane = tid & 63;
    int w = tid >> 6;
    int wr = w >> 1, wc = w & 1;
    int row0 = blockIdx.y * 128;
    int col0 = blockIdx.x * 128;
    f32x4 acc[4][4] = {};

    for (int kt = 0; kt < K; kt += 32) {
        if (kt) __syncthreads();
        #pragma unroll
        for (int L = 0; L < 2; ++L) {
            int cb = L * 256 + w * 64;
            int c = cb + lane;
            int r = c >> 2;
            int ko = (c & 3) * 8;
            int rr = min(row0 + r, M - 1);
            async_copy16(A + (size_t)rr * K + kt + ko, sA + (size_t)cb * 8);
        }
        #pragma unroll
        for (int L = 0; L < 2; ++L) {
            int cb = L * 256 + w * 64;
            int c = cb + lane;
            int nr = c >> 2;
            int ko = (c & 3) * 8;
            async_copy16(BT + (size_t)(col0 + nr) * K + kt + ko, sB + (size_t)cb * 8);
        }
        __syncthreads();
        bf16x8 af[4], bfr[4];
        #pragma unroll
        for (int i = 0; i < 4; ++i) {
            int row = wr * 64 + i * 16 + (lane & 15);
            af[i] = *(const bf16x8*)(sA + row * 32 + (lane >> 4) * 8);
        }
        #pragma unroll
        for (int j = 0; j < 4; ++j) {
            int n = wc * 64 + j * 16 + (lane & 15);
            bfr[j] = *(const bf16x8*)(sB + n * 32 + (lane >> 4) * 8);
        }
        #pragma unroll
        for (int i = 0; i < 4; ++i)
            #pragma unroll
            for (int j = 0; j < 4; ++j)
                acc[i][j] = __builtin_amdgcn_mfma_f32_16x16x32_bf16(af[i], bfr[j], acc[i][j], 0, 0, 0);
    }

    #pragma unroll
    for (int i = 0; i < 4; ++i) {
        #pragma unroll
        for (int j = 0; j < 4; ++j) {
            int col = col0 + wc * 64 + j * 16 + (lane & 15);
            if (col >= Nact) continue;
            float bv = bias[col];
            #pragma unroll
            for (int r = 0; r < 4; ++r) {
                int row = row0 + wr * 64 + i * 16 + (lane >> 4) * 4 + r;
                if (row >= M) continue;
                float v = acc[i][j][r] + bv;
                if (MODE == 0) {
                    v = fmaxf(v, 0.0f);
                    ((ushort*)Cout)[(size_t)row * ldc + col] = f2bf(v);
                } else if (MODE == 1) {
                    v = softplus_fast(v);
                    ((float*)Cout)[(size_t)row * ldc + col] = v;
                } else {
                    ((float*)Cout)[(size_t)row * ldc + col] = v;
                }
            }
        }
    }
}

// GEMM3: A = tanh(sp * mr) computed on the fly from fp32 mr[M,500]; K padded to 512.
__global__ __launch_bounds__(256)
void gemm_tanh(const float* __restrict__ Ain, const ushort* __restrict__ BT,
               const float* __restrict__ bias, float* __restrict__ Cout,
               int M, int Nact, int ldc, const float* __restrict__ thr) {
    const int K = 512, KA = 500;
    __shared__ ushort sA[128 * 32];
    __shared__ ushort sB[128 * 32];
    int tid = threadIdx.x;
    int lane = tid & 63;
    int w = tid >> 6;
    int wr = w >> 1, wc = w & 1;
    int row0 = blockIdx.y * 128;
    int col0 = blockIdx.x * 128;
    float t = *thr;
    float sp = softplus_fast(t);
    f32x4 acc[4][4] = {};

    int r = tid >> 1;
    int kh = (tid & 1) * 16;
    int rr_a = min(row0 + r, M - 1);
    const float* arow = Ain + (size_t)rr_a * KA;

    for (int kt = 0; kt < K; kt += 32) {
        if (kt) __syncthreads();
        // A: manual stage with fused tanh + cast
        float vals[16];
        int kb = kt + kh;
        if (kb + 16 <= KA) {
            #pragma unroll
            for (int q = 0; q < 4; ++q) {
                float4 f = *(const float4*)(arow + kb + q * 4);
                vals[q * 4 + 0] = f.x; vals[q * 4 + 1] = f.y;
                vals[q * 4 + 2] = f.z; vals[q * 4 + 3] = f.w;
            }
        } else {
            #pragma unroll
            for (int q = 0; q < 16; ++q) {
                int k = kb + q;
                vals[q] = (k < KA) ? arow[k] : 0.0f;
            }
        }
        ushort us[16];
        #pragma unroll
        for (int q = 0; q < 16; ++q) us[q] = f2bf(tanh_fast(sp * vals[q]));
        *(uint4*)(sA + r * 32 + kh) = *(const uint4*)(us);
        *(uint4*)(sA + r * 32 + kh + 8) = *(const uint4*)(us + 8);
        // B: async stage
        #pragma unroll
        for (int L = 0; L < 2; ++L) {
            int cb = L * 256 + w * 64;
            int c = cb + lane;
            int nr = c >> 2;
            int ko = (c & 3) * 8;
            async_copy16(BT + (size_t)(col0 + nr) * K + kt + ko, sB + (size_t)cb * 8);
        }
        __syncthreads();
        bf16x8 af[4], bfr[4];
        #pragma unroll
        for (int i = 0; i < 4; ++i) {
            int row = wr * 64 + i * 16 + (lane & 15);
            af[i] = *(const bf16x8*)(sA + row * 32 + (lane >> 4) * 8);
        }
        #pragma unroll
        for (int j = 0; j < 4; ++j) {
            int n = wc * 64 + j * 16 + (lane & 15);
            bfr[j] = *(const bf16x8*)(sB + n * 32 + (lane >> 4) * 8);
        }
        #pragma unroll
        for (int i = 0; i < 4; ++i)
            #pragma unroll
            for (int j = 0; j < 4; ++j)
                acc[i][j] = __builtin_amdgcn_mfma_f32_16x16x32_bf16(af[i], bfr[j], acc[i][j], 0, 0, 0);
    }

    #pragma unroll
    for (int i = 0; i < 4; ++i) {
        #pragma unroll
        for (int j = 0; j < 4; ++j) {
            int col = col0 + wc * 64 + j * 16 + (lane & 15);
            if (col >= Nact) continue;
            float bv = bias[col];
            #pragma unroll
            for (int rix = 0; rix < 4; ++rix) {
                int row = row0 + wr * 64 + i * 16 + (lane >> 4) * 4 + rix;
                if (row >= M) continue;
                Cout[(size_t)row * ldc + col] = acc[i][j][rix] + bv;
            }
        }
    }
}

// ---------------- launch ----------------

extern "C" void kernel_launch(void* const* d_in, const int* in_sizes, int n_in,
                              void* d_out, int out_size, void* d_ws, size_t ws_size,
                              hipStream_t stream) {
    const float* x    = (const float*)d_in[0];
    const int*   ei   = (const int*)d_in[1];
    const float* W1   = (const float*)d_in[2];
    const float* b1   = (const float*)d_in[3];
    const float* W2   = (const float*)d_in[4];
    const float* b2   = (const float*)d_in[5];
    const float* Wout = (const float*)d_in[6];
    const float* bout = (const float*)d_in[7];
    const float* thr  = (const float*)d_in[8];

    int N = in_sizes[0] / DIN;
    int E = in_sizes[1] / 2;
    const int* srcI = ei;
    const int* dstI = ei + E;

    char* wsp = (char*)d_ws;
    size_t o = 0;
    auto alloc = [&](size_t bytes) -> void* {
        void* p = wsp + o;
        o = (o + bytes + 255) & ~(size_t)255;
        return p;
    };
    int*    deg   = (int*)alloc((size_t)N * 4);
    float*  dinv  = (float*)alloc((size_t)N * 4);
    int*    rp    = (int*)alloc((size_t)(N + 1) * 4);
    int*    bsum  = (int*)alloc(1024);
    int*    bcur  = (int*)alloc(MAXB * 4);
    int*    col   = (int*)alloc((size_t)E * 4);
    ushort* W1T   = (ushort*)alloc((size_t)256 * 128 * 2);
    ushort* W2T   = (ushort*)alloc((size_t)512 * 256 * 2);
    ushort* WoutT = (ushort*)alloc((size_t)128 * 512 * 2);
    ushort* bufA  = (ushort*)alloc((size_t)N * 256 * 2);  // xbf+xa, later ha
    ushort* hbuf  = (ushort*)alloc((size_t)N * 256 * 2);  // h bf16 (pairBuf before gemm1)

    ushort* xbf = bufA;                       // [N,128] bf16
    ushort* xa  = bufA + (size_t)N * 128;     // [N,128] bf16
    ushort* ha  = bufA;                       // [N,256] bf16 (reuses xbf+xa)
    uint* pairBuf = (uint*)hbuf;              // [E] packed edges (dead before gemm1 writes hbuf)

    float* mr   = (float*)d_out;                    // [N,500]
    float* yout = (float*)d_out + (size_t)N * MODD; // [N,100]

    int mtiles = (N + 127) / 128;
    int NB = (N + (1 << BSH) - 1) >> BSH;           // node-range buckets (196 for N=100K)

    // --- CSR build ---
    hipMemsetAsync(deg, 0, (size_t)N * 4, stream);
    count_deg<<<(E + 255) / 256, 256, 0, stream>>>(dstI, deg, E);
    compute_dinv<<<(N + 255) / 256, 256, 0, stream>>>(deg, dinv, N);
    int nb = (N + 1023) / 1024;
    scan_block<<<nb, 1024, 0, stream>>>(deg, rp, bsum, N);
    scan_bsums<<<1, 64, 0, stream>>>(bsum, nb);
    scan_add<<<(N + 256) / 256, 256, 0, stream>>>(rp, bsum, N, nb);
    // binned 2-pass edge scatter
    init_bucket_cursor<<<1, 256, 0, stream>>>(rp, bcur, NB);
    partition_edges<<<(E + PCH - 1) / PCH, 256, 0, stream>>>(srcI, dstI, bcur, pairBuf, E, NB);
    bucket_scatter<<<NB, 512, 0, stream>>>(pairBuf, rp, col, N);

    // --- weight prep ---
    cast_f32_bf16<<<((N * DIN / 4) + 255) / 256, 256, 0, stream>>>(x, xbf, N * DIN / 4);
    transpose_cast<<<(256 * 128 + 255) / 256, 256, 0, stream>>>(W1, W1T, 128, 256, 128, 256);
    transpose_cast<<<(512 * 256 + 255) / 256, 256, 0, stream>>>(W2, W2T, 256, 500, 256, 512);
    transpose_cast<<<(128 * 512 + 255) / 256, 256, 0, stream>>>(Wout, WoutT, 500, 100, 512, 128);

    // --- conv1 ---
    aggregate128<<<(N + 3) / 4, 256, 0, stream>>>(xbf, xa, rp, col, dinv, N);
    gemm_bt<128, 0><<<dim3(2, mtiles), 256, 0, stream>>>(xa, W1T, b1, hbuf, N, HID, HID);

    // --- conv2 ---
    aggregate256<<<(N + 3) / 4, 256, 0, stream>>>(hbuf, ha, rp, col, dinv, N);
    gemm_bt<256, 1><<<dim3(4, mtiles), 256, 0, stream>>>(ha, W2T, b2, mr, N, MODD, MODD);

    // --- head: y = tanh(sp*mr) @ Wout + bout ---
    gemm_tanh<<<dim3(1, mtiles), 256, 0, stream>>>(mr, WoutT, bout, yout, N, OUTD, OUTD, thr);
}

// Round 4
// 1072.380 us; speedup vs baseline: 1.2377x; 1.0631x over previous
//
#include <hip/hip_runtime.h>
#include <cstdint>
#include <cstddef>

#define DIN 128
#define HID 256
#define MODD 500
#define OUTD 100

typedef unsigned int uint;
typedef unsigned short ushort;
typedef __attribute__((ext_vector_type(8))) __bf16 bf16x8;
typedef __attribute__((ext_vector_type(4))) float f32x4;

__device__ __forceinline__ float bf2f(ushort u) {
    return __uint_as_float(((uint)u) << 16);
}
__device__ __forceinline__ ushort f2bf(float f) {
    uint u = __float_as_uint(f);
    return (ushort)((u + 0x7FFF + ((u >> 16) & 1)) >> 16);
}
__device__ __forceinline__ uint packbf2(float lo, float hi) {
    return (uint)f2bf(lo) | ((uint)f2bf(hi) << 16);
}
__device__ __forceinline__ void async_copy16(const void* g, void* l) {
    __builtin_amdgcn_global_load_lds((const __attribute__((address_space(1))) void*)g,
                                     (__attribute__((address_space(3))) void*)l, 16, 0, 0);
}
__device__ __forceinline__ float tanh_fast(float x) {
    // x >= 0 in our use (softplus output); stable both ends anyway
    return 1.0f - 2.0f / (__expf(2.0f * x) + 1.0f);
}
// stable fast softplus: max(v,0) + log(1 + exp(-|v|)); ~6 VALU ops vs libm's ~60+
__device__ __forceinline__ float softplus_fast(float v) {
    return fmaxf(v, 0.0f) + __logf(1.0f + __expf(-fabsf(v)));
}
// accumulate 8 bf16 (one uint4) scaled by w into a[0..8)
__device__ __forceinline__ void acc8(float* a, uint4 v, float w) {
    a[0] += w * bf2f((ushort)(v.x & 0xFFFF));
    a[1] += w * bf2f((ushort)(v.x >> 16));
    a[2] += w * bf2f((ushort)(v.y & 0xFFFF));
    a[3] += w * bf2f((ushort)(v.y >> 16));
    a[4] += w * bf2f((ushort)(v.z & 0xFFFF));
    a[5] += w * bf2f((ushort)(v.z >> 16));
    a[6] += w * bf2f((ushort)(v.w & 0xFFFF));
    a[7] += w * bf2f((ushort)(v.w >> 16));
}

// ---------------- degree / CSR build ----------------

__global__ void count_deg(const int* __restrict__ dst, int* __restrict__ deg, int E) {
    int e = blockIdx.x * blockDim.x + threadIdx.x;
    if (e < E) atomicAdd(&deg[dst[e]], 1);
}

__global__ void compute_dinv(const int* __restrict__ deg, float* __restrict__ dinv, int N) {
    int i = blockIdx.x * blockDim.x + threadIdx.x;
    if (i < N) dinv[i] = rsqrtf((float)deg[i] + 2.0f);
}

// 3-phase scan: per-block scan -> scan of block sums -> add offsets
__global__ void scan_block(const int* __restrict__ deg, int* __restrict__ rp,
                           int* __restrict__ bsum, int n) {
    __shared__ int wsum[16];
    int tid = threadIdx.x;
    int lane = tid & 63;
    int w = tid >> 6;
    int i = blockIdx.x * 1024 + tid;
    int v = (i < n) ? deg[i] : 0;
    int x = v;
    #pragma unroll
    for (int off = 1; off < 64; off <<= 1) {
        int t = __shfl_up(x, off);
        if (lane >= off) x += t;
    }
    if (lane == 63) wsum[w] = x;
    __syncthreads();
    if (tid == 0) {
        int s = 0;
        #pragma unroll
        for (int k = 0; k < 16; ++k) { int t = wsum[k]; wsum[k] = s; s += t; }
        bsum[blockIdx.x] = s;
    }
    __syncthreads();
    if (i < n) rp[i] = wsum[w] + (x - v);
}

__global__ void scan_bsums(int* __restrict__ bsum, int nb) {
    if (threadIdx.x == 0 && blockIdx.x == 0) {
        int s = 0;
        for (int k = 0; k < nb; ++k) { int t = bsum[k]; bsum[k] = s; s += t; }
        bsum[nb] = s;
    }
}

__global__ void scan_add(int* __restrict__ rp, const int* __restrict__ bsum, int n, int nb) {
    int i = blockIdx.x * blockDim.x + threadIdx.x;
    if (i < n) rp[i] += bsum[i >> 10];
    else if (i == n) rp[n] = bsum[nb];
}

// ---------------- binned edge scatter ----------------
// Buckets of 512 consecutive dst nodes occupy contiguous CSR ranges
// [rp[b*512], rp[(b+1)*512]). Pass 1 partitions edges into those ranges with
// per-block LDS histogramming (coalesced run writes, ~1 global atomic per
// (block,bucket)). Pass 2 builds final col[] per bucket with LDS cursors, so
// random writes stay inside a ~64KB L2-resident window.
// Packing: src (<2^20) in low 20 bits, dst offset (<512) in bits 20..28.

#define BSH 9
#define MAXB 256
#define PCH 8192

__global__ void init_bucket_cursor(const int* __restrict__ rp, int* __restrict__ bcur,
                                   int NB) {
    int b = blockIdx.x * blockDim.x + threadIdx.x;
    if (b < NB) bcur[b] = rp[b << BSH];
}

__global__ __launch_bounds__(256)
void partition_edges(const int* __restrict__ src, const int* __restrict__ dst,
                     int* __restrict__ bcur, uint* __restrict__ pairBuf,
                     int E, int NB) {
    __shared__ int hist[MAXB];
    __shared__ int gbase[MAXB];
    int tid = threadIdx.x;
    int e0 = blockIdx.x * PCH;
    int e1 = min(e0 + PCH, E);
    for (int b = tid; b < NB; b += 256) hist[b] = 0;
    __syncthreads();
    for (int e = e0 + tid; e < e1; e += 256) {
        int d = dst[e];
        atomicAdd(&hist[d >> BSH], 1);
    }
    __syncthreads();
    for (int b = tid; b < NB; b += 256) {
        int h = hist[b];
        gbase[b] = h ? atomicAdd(&bcur[b], h) : 0;
        hist[b] = 0;
    }
    __syncthreads();
    for (int e = e0 + tid; e < e1; e += 256) {
        int d = dst[e];
        int s = src[e];
        int b = d >> BSH;
        int idx = gbase[b] + atomicAdd(&hist[b], 1);
        pairBuf[idx] = (uint)s | ((uint)(d & ((1 << BSH) - 1)) << 20);
    }
}

__global__ __launch_bounds__(512)
void bucket_scatter(const uint* __restrict__ pairBuf, const int* __restrict__ rp,
                    int* __restrict__ col, int N) {
    __shared__ int lcur[1 << BSH];
    int b = blockIdx.x;
    int n0 = b << BSH;
    int nn = min(1 << BSH, N - n0);
    int tid = threadIdx.x;
    for (int i = tid; i < nn; i += 512) lcur[i] = rp[n0 + i];
    __syncthreads();
    int start = rp[n0];
    int end = rp[min(n0 + (1 << BSH), N)];
    for (int e = start + tid; e < end; e += 512) {
        uint v = pairBuf[e];
        int doff = v >> 20;
        int s = v & 0xFFFFF;
        int pos = atomicAdd(&lcur[doff], 1);
        col[pos] = s;
    }
}

// ---------------- casts / transposes ----------------

__global__ void cast_f32_bf16(const float* __restrict__ src, ushort* __restrict__ dst, int n4) {
    int i = blockIdx.x * blockDim.x + threadIdx.x;
    if (i < n4) {
        float4 v = ((const float4*)src)[i];
        ushort4 o;
        o.x = f2bf(v.x); o.y = f2bf(v.y); o.z = f2bf(v.z); o.w = f2bf(v.w);
        ((ushort4*)dst)[i] = o;
    }
}

// src[K][N] fp32 -> dst[Npad][Kpad] bf16 (zero padded)
__global__ void transpose_cast(const float* __restrict__ src, ushort* __restrict__ dst,
                               int K, int N, int Kpad, int Npad) {
    int idx = blockIdx.x * blockDim.x + threadIdx.x;
    if (idx >= Npad * Kpad) return;
    int n = idx / Kpad, k = idx - n * Kpad;
    float v = (n < N && k < K) ? src[(size_t)k * N + n] : 0.0f;
    dst[idx] = f2bf(v);
}

// ---------------- aggregation (gather over CSR, bf16 rows, fp32 accum) ----------------
// Y[n] = 2*dinv[n]^2 * X[n] + sum_{e in in(n)} dinv[src]*dinv[n] * X[src]
// Split-wave wide gathers: each lane loads uint4 (16B); the 64-lane wave covers
// 2 rows (D=256) / 4 rows (D=128) per load instruction. Each sub-wave group
// accumulates a disjoint parity class of the node's edges into its own 8-f32
// partial accumulator; one shfl_xor reduce at the end. Same bytes as before,
// half/quarter the load instructions, 2-4x bytes in flight per vmcnt slot.

// D = 128 bf16 (256B rows = 16 uint4): 4 groups of 16 lanes, 4 rows/load
__global__ void aggregate128(const ushort* __restrict__ X, ushort* __restrict__ Y,
                             const int* __restrict__ rp, const int* __restrict__ col,
                             const float* __restrict__ dinv, int N) {
    int gw = blockIdx.x * (blockDim.x >> 6) + (threadIdx.x >> 6);
    int lane = threadIdx.x & 63;
    if (gw >= N) return;
    int g = lane >> 4;        // edge parity class 0..3
    int sub = lane & 15;      // uint4 index within row
    float di = dinv[gw];
    float sc = 2.0f * di * di;
    const uint4* Xr = (const uint4*)X;   // row stride = 16 uint4
    float a[8] = {};
    if (g == 0) acc8(a, Xr[(size_t)gw * 16 + sub], sc);   // self term
    int e = rp[gw], end = rp[gw + 1];
    int base = e;
    for (; base + 8 <= end; base += 8) {
        int c0 = col[base + g];
        int c1 = col[base + 4 + g];
        float w0 = dinv[c0] * di, w1 = dinv[c1] * di;
        uint4 v0 = Xr[(size_t)c0 * 16 + sub];
        uint4 v1 = Xr[(size_t)c1 * 16 + sub];
        acc8(a, v0, w0);
        acc8(a, v1, w1);
    }
    if (base + 4 <= end) {
        int c0 = col[base + g];
        float w0 = dinv[c0] * di;
        acc8(a, Xr[(size_t)c0 * 16 + sub], w0);
        base += 4;
    }
    int rem = end - base;    // 0..3
    if (g < rem) {
        int c0 = col[base + g];
        float w0 = dinv[c0] * di;
        acc8(a, Xr[(size_t)c0 * 16 + sub], w0);
    }
    #pragma unroll
    for (int q = 0; q < 8; ++q) {
        a[q] += __shfl_xor(a[q], 16);
        a[q] += __shfl_xor(a[q], 32);
    }
    if (g == 0) {
        uint4 o;
        o.x = packbf2(a[0], a[1]);
        o.y = packbf2(a[2], a[3]);
        o.z = packbf2(a[4], a[5]);
        o.w = packbf2(a[6], a[7]);
        ((uint4*)Y)[(size_t)gw * 16 + sub] = o;
    }
}

// D = 256 bf16 (512B rows = 32 uint4): 2 groups of 32 lanes, 2 rows/load
__global__ void aggregate256(const ushort* __restrict__ X, ushort* __restrict__ Y,
                             const int* __restrict__ rp, const int* __restrict__ col,
                             const float* __restrict__ dinv, int N) {
    int gw = blockIdx.x * (blockDim.x >> 6) + (threadIdx.x >> 6);
    int lane = threadIdx.x & 63;
    if (gw >= N) return;
    int g = lane >> 5;        // edge parity class 0..1
    int sub = lane & 31;      // uint4 index within row
    float di = dinv[gw];
    float sc = 2.0f * di * di;
    const uint4* Xr = (const uint4*)X;   // row stride = 32 uint4
    float a[8] = {};
    if (g == 0) acc8(a, Xr[(size_t)gw * 32 + sub], sc);   // self term
    int e = rp[gw], end = rp[gw + 1];
    int base = e;
    for (; base + 4 <= end; base += 4) {
        int c0 = col[base + g];
        int c1 = col[base + 2 + g];
        float w0 = dinv[c0] * di, w1 = dinv[c1] * di;
        uint4 v0 = Xr[(size_t)c0 * 32 + sub];
        uint4 v1 = Xr[(size_t)c1 * 32 + sub];
        acc8(a, v0, w0);
        acc8(a, v1, w1);
    }
    if (base + 2 <= end) {
        int c0 = col[base + g];
        float w0 = dinv[c0] * di;
        acc8(a, Xr[(size_t)c0 * 32 + sub], w0);
        base += 2;
    }
    if (base < end && g == 0) {   // one leftover edge
        int c0 = col[base];
        float w0 = dinv[c0] * di;
        acc8(a, Xr[(size_t)c0 * 32 + sub], w0);
    }
    #pragma unroll
    for (int q = 0; q < 8; ++q) a[q] += __shfl_xor(a[q], 32);
    if (g == 0) {
        uint4 o;
        o.x = packbf2(a[0], a[1]);
        o.y = packbf2(a[2], a[3]);
        o.z = packbf2(a[4], a[5]);
        o.w = packbf2(a[6], a[7]);
        ((uint4*)Y)[(size_t)gw * 32 + sub] = o;
    }
}

// ---------------- bf16 MFMA GEMM (m97 structure) ----------------
// C[M,Nact] = epi(A[M,K]_bf16 @ BT[Npad,K]_bf16^T + bias)
// BM=128, BN=128, BK=32, 256 threads = 4 waves, each wave 64x64 (4x4 MFMA tiles)
// MODE 0: relu -> bf16 store
// MODE 2: plain -> f32 store
// MODE 3: softplus -> f32 store (Cout) AND tanh(sp*softplus) -> bf16 store (C2, ld 512,
//         cols [Nact,512) zeroed) — feeds the head GEMM without an f32 re-read.

template<int K, int MODE>
__global__ __launch_bounds__(256)
void gemm_bt(const ushort* __restrict__ A, const ushort* __restrict__ BT,
             const float* __restrict__ bias, void* __restrict__ Cout,
             int M, int Nact, int ldc, ushort* __restrict__ C2,
             const float* __restrict__ thr) {
    __shared__ ushort sA[128 * 32];
    __shared__ ushort sB[128 * 32];
    int tid = threadIdx.x;
    int lane = tid & 63;
    int w = tid >> 6;
    int wr = w >> 1, wc = w & 1;
    int row0 = blockIdx.y * 128;
    int col0 = blockIdx.x * 128;
    float sp = 0.0f;
    if (MODE == 3) sp = softplus_fast(*thr);
    f32x4 acc[4][4] = {};

    for (int kt = 0; kt < K; kt += 32) {
        if (kt) __syncthreads();
        #pragma unroll
        for (int L = 0; L < 2; ++L) {
            int cb = L * 256 + w * 64;
            int c = cb + lane;
            int r = c >> 2;
            int ko = (c & 3) * 8;
            int rr = min(row0 + r, M - 1);
            async_copy16(A + (size_t)rr * K + kt + ko, sA + (size_t)cb * 8);
        }
        #pragma unroll
        for (int L = 0; L < 2; ++L) {
            int cb = L * 256 + w * 64;
            int c = cb + lane;
            int nr = c >> 2;
            int ko = (c & 3) * 8;
            async_copy16(BT + (size_t)(col0 + nr) * K + kt + ko, sB + (size_t)cb * 8);
        }
        __syncthreads();
        bf16x8 af[4], bfr[4];
        #pragma unroll
        for (int i = 0; i < 4; ++i) {
            int row = wr * 64 + i * 16 + (lane & 15);
            af[i] = *(const bf16x8*)(sA + row * 32 + (lane >> 4) * 8);
        }
        #pragma unroll
        for (int j = 0; j < 4; ++j) {
            int n = wc * 64 + j * 16 + (lane & 15);
            bfr[j] = *(const bf16x8*)(sB + n * 32 + (lane >> 4) * 8);
        }
        #pragma unroll
        for (int i = 0; i < 4; ++i)
            #pragma unroll
            for (int j = 0; j < 4; ++j)
                acc[i][j] = __builtin_amdgcn_mfma_f32_16x16x32_bf16(af[i], bfr[j], acc[i][j], 0, 0, 0);
    }

    #pragma unroll
    for (int i = 0; i < 4; ++i) {
        #pragma unroll
        for (int j = 0; j < 4; ++j) {
            int col = col0 + wc * 64 + j * 16 + (lane & 15);
            if (MODE == 3) {
                bool act = (col < Nact);
                float bv = act ? bias[col] : 0.0f;
                #pragma unroll
                for (int r = 0; r < 4; ++r) {
                    int row = row0 + wr * 64 + i * 16 + (lane >> 4) * 4 + r;
                    if (row >= M) continue;
                    if (act) {
                        float v = softplus_fast(acc[i][j][r] + bv);
                        ((float*)Cout)[(size_t)row * ldc + col] = v;
                        C2[(size_t)row * 512 + col] = f2bf(tanh_fast(sp * v));
                    } else {
                        C2[(size_t)row * 512 + col] = 0;
                    }
                }
            } else {
                if (col >= Nact) continue;
                float bv = bias[col];
                #pragma unroll
                for (int r = 0; r < 4; ++r) {
                    int row = row0 + wr * 64 + i * 16 + (lane >> 4) * 4 + r;
                    if (row >= M) continue;
                    float v = acc[i][j][r] + bv;
                    if (MODE == 0) {
                        v = fmaxf(v, 0.0f);
                        ((ushort*)Cout)[(size_t)row * ldc + col] = f2bf(v);
                    } else {
                        ((float*)Cout)[(size_t)row * ldc + col] = v;
                    }
                }
            }
        }
    }
}

// ---------------- launch ----------------

extern "C" void kernel_launch(void* const* d_in, const int* in_sizes, int n_in,
                              void* d_out, int out_size, void* d_ws, size_t ws_size,
                              hipStream_t stream) {
    const float* x    = (const float*)d_in[0];
    const int*   ei   = (const int*)d_in[1];
    const float* W1   = (const float*)d_in[2];
    const float* b1   = (const float*)d_in[3];
    const float* W2   = (const float*)d_in[4];
    const float* b2   = (const float*)d_in[5];
    const float* Wout = (const float*)d_in[6];
    const float* bout = (const float*)d_in[7];
    const float* thr  = (const float*)d_in[8];

    int N = in_sizes[0] / DIN;
    int E = in_sizes[1] / 2;
    const int* srcI = ei;
    const int* dstI = ei + E;

    char* wsp = (char*)d_ws;
    size_t o = 0;
    auto alloc = [&](size_t bytes) -> void* {
        void* p = wsp + o;
        o = (o + bytes + 255) & ~(size_t)255;
        return p;
    };
    int*    deg   = (int*)alloc((size_t)N * 4);
    float*  dinv  = (float*)alloc((size_t)N * 4);
    int*    rp    = (int*)alloc((size_t)(N + 1) * 4);
    int*    bsum  = (int*)alloc(1024);
    int*    bcur  = (int*)alloc(MAXB * 4);
    ushort* W1T   = (ushort*)alloc((size_t)256 * 128 * 2);
    ushort* W2T   = (ushort*)alloc((size_t)512 * 256 * 2);
    ushort* WoutT = (ushort*)alloc((size_t)128 * 512 * 2);
    ushort* bufA  = (ushort*)alloc((size_t)N * 256 * 2);  // xbf+xa, later ha
    // col + hbuf live contiguously; after aggregate256 both are dead and the
    // region is reused as pbf [N,512] bf16 (tanh(sp*softplus) activations).
    size_t  col_off = o;
    int*    col   = (int*)alloc((size_t)E * 4);
    ushort* hbuf  = (ushort*)alloc((size_t)N * 256 * 2);  // h bf16 (pairBuf before gemm1)
    size_t  pbf_need = col_off + (size_t)N * 512 * 2;
    if (o < pbf_need) o = (pbf_need + 255) & ~(size_t)255;
    ushort* pbf = (ushort*)(wsp + col_off);               // [N,512] bf16

    ushort* xbf = bufA;                       // [N,128] bf16
    ushort* xa  = bufA + (size_t)N * 128;     // [N,128] bf16
    ushort* ha  = bufA;                       // [N,256] bf16 (reuses xbf+xa)
    uint* pairBuf = (uint*)hbuf;              // [E] packed edges (dead before gemm1 writes hbuf)

    float* mr   = (float*)d_out;                    // [N,500]
    float* yout = (float*)d_out + (size_t)N * MODD; // [N,100]

    int mtiles = (N + 127) / 128;
    int NB = (N + (1 << BSH) - 1) >> BSH;           // node-range buckets (196 for N=100K)

    // --- CSR build ---
    hipMemsetAsync(deg, 0, (size_t)N * 4, stream);
    count_deg<<<(E + 255) / 256, 256, 0, stream>>>(dstI, deg, E);
    compute_dinv<<<(N + 255) / 256, 256, 0, stream>>>(deg, dinv, N);
    int nb = (N + 1023) / 1024;
    scan_block<<<nb, 1024, 0, stream>>>(deg, rp, bsum, N);
    scan_bsums<<<1, 64, 0, stream>>>(bsum, nb);
    scan_add<<<(N + 256) / 256, 256, 0, stream>>>(rp, bsum, N, nb);
    // binned 2-pass edge scatter
    init_bucket_cursor<<<1, 256, 0, stream>>>(rp, bcur, NB);
    partition_edges<<<(E + PCH - 1) / PCH, 256, 0, stream>>>(srcI, dstI, bcur, pairBuf, E, NB);
    bucket_scatter<<<NB, 512, 0, stream>>>(pairBuf, rp, col, N);

    // --- weight prep ---
    cast_f32_bf16<<<((N * DIN / 4) + 255) / 256, 256, 0, stream>>>(x, xbf, N * DIN / 4);
    transpose_cast<<<(256 * 128 + 255) / 256, 256, 0, stream>>>(W1, W1T, 128, 256, 128, 256);
    transpose_cast<<<(512 * 256 + 255) / 256, 256, 0, stream>>>(W2, W2T, 256, 500, 256, 512);
    transpose_cast<<<(128 * 512 + 255) / 256, 256, 0, stream>>>(Wout, WoutT, 500, 100, 512, 128);

    // --- conv1 ---
    aggregate128<<<(N + 3) / 4, 256, 0, stream>>>(xbf, xa, rp, col, dinv, N);
    gemm_bt<128, 0><<<dim3(2, mtiles), 256, 0, stream>>>(xa, W1T, b1, hbuf, N, HID, HID,
                                                         nullptr, nullptr);

    // --- conv2 (epilogue also emits tanh(sp*softplus) bf16 into pbf) ---
    aggregate256<<<(N + 3) / 4, 256, 0, stream>>>(hbuf, ha, rp, col, dinv, N);
    gemm_bt<256, 3><<<dim3(4, mtiles), 256, 0, stream>>>(ha, W2T, b2, mr, N, MODD, MODD,
                                                         pbf, thr);

    // --- head: y = pbf @ Wout + bout ---
    gemm_bt<512, 2><<<dim3(1, mtiles), 256, 0, stream>>>(pbf, WoutT, bout, yout, N, OUTD, OUTD,
                                                         nullptr, nullptr);
}